// Round 5
// baseline (586.701 us; speedup 1.0000x reference)
//
#include <hip/hip_runtime.h>
#include <hip/hip_bf16.h>

// TemporalAttention fused kernel for MI355X (gfx950), round 5.
// 512 threads = 8 waves per block, ONE head per wave, single pass:
// halves the per-wave critical path vs round 4 and doubles waves/CU.
// Q/K/P/V fragments all via in-register transpose (round-3-verified algebra).
// LDS 32KB (X stage -> att -> f32 epilogue halves). launch_bounds(512,4):
// VGPR cap 128 vs ~105 est. peak live -> no spills (rounds 3/4 lesson).

namespace {

constexpr int S_LEN = 64;
constexpr int DM    = 256;
constexpr int NQKV  = 3 * DM * DM;

typedef float f32x4 __attribute__((ext_vector_type(4)));
typedef short s16x8 __attribute__((ext_vector_type(8)));

union BF2 { __hip_bfloat162 h; unsigned u; };
__device__ __forceinline__ unsigned pkbf2(float a, float b) {
  float2 t; t.x = a; t.y = b;
  BF2 cv; cv.h = __float22bfloat162_rn(t);
  return cv.u;
}

// In-register fragment transpose (verified rounds 3/4). Source: two f32x4
// accumulators (idx = 4*gs + r along the transposed dim, same c). Target:
// s16x8 MFMA A/B-fragment for lane (g,c).
__device__ __forceinline__ s16x8 xpose_frag(f32x4 a0, f32x4 a1, int c, int g) {
  const int src0 = ((g & 1) << 5) + c;
  const int src1 = src0 + 16;
  unsigned p00 = pkbf2(a0[0], a0[1]);
  unsigned p01 = pkbf2(a0[2], a0[3]);
  unsigned p10 = pkbf2(a1[0], a1[1]);
  unsigned p11 = pkbf2(a1[2], a1[3]);
  const bool hi = (g & 2) != 0;
  unsigned w0a = (unsigned)__shfl((int)p00, src0);
  unsigned w0b = (unsigned)__shfl((int)p10, src0);
  unsigned w1a = (unsigned)__shfl((int)p01, src0);
  unsigned w1b = (unsigned)__shfl((int)p11, src0);
  unsigned w2a = (unsigned)__shfl((int)p00, src1);
  unsigned w2b = (unsigned)__shfl((int)p10, src1);
  unsigned w3a = (unsigned)__shfl((int)p01, src1);
  unsigned w3b = (unsigned)__shfl((int)p11, src1);
  union { s16x8 v; unsigned u[4]; } r;
  r.u[0] = hi ? w0b : w0a;
  r.u[1] = hi ? w1b : w1a;
  r.u[2] = hi ? w2b : w2a;
  r.u[3] = hi ? w3b : w3a;
  return r.v;
}

} // namespace

// ---- prep: f32 weights -> bf16 in workspace ----
__global__ void ta_prep_weights(const float* __restrict__ wqkv,
                                const float* __restrict__ wproj,
                                unsigned short* __restrict__ wsb) {
  const int i = (blockIdx.x * 256 + (int)threadIdx.x) * 4;
  f32x4 v = (i < NQKV) ? *(const f32x4*)(wqkv + i)
                       : *(const f32x4*)(wproj + (i - NQKV));
  unsigned u0 = pkbf2(v[0], v[1]);
  unsigned u1 = pkbf2(v[2], v[3]);
  *(uint2*)(wsb + i) = make_uint2(u0, u1);
}

__global__ void __launch_bounds__(512, 4)
ta_fused_kernel(const float* __restrict__ x,
                const unsigned short* __restrict__ wq_bf,   // [768][256] bf16
                const float* __restrict__ bqkv,
                const unsigned short* __restrict__ wp_bf,   // [256][256] bf16
                const float* __restrict__ bproj,
                float* __restrict__ out)
{
  // LDS 32KB: xls[64][256] bf16 (X, swizzled) -> att[64][256] -> f32 [32][256] halves.
  __shared__ __align__(16) unsigned short lds[16384];

  const int bn = blockIdx.x;
  const int tid = (int)threadIdx.x;
  const int w = tid >> 6;       // wave 0..7 = head
  const int l = tid & 63;
  const int g = l >> 4;
  const int c = l & 15;
  const int c7s = (c & 7) << 3;
  const int h = w;

  const float* __restrict__ xb = x + (size_t)bn * (S_LEN * DM);

  // ---- cooperative stage X -> LDS bf16 (swizzled) ----
#pragma unroll
  for (int it = 0; it < 4; ++it) {
    const int e = (it * 512 + tid) * 8;
    const int row = e >> 8;
    f32x4 a = *(const f32x4*)(xb + e);
    f32x4 b = *(const f32x4*)(xb + e + 4);
    union { s16x8 v; unsigned u[4]; } r;
    r.u[0] = pkbf2(a[0], a[1]); r.u[1] = pkbf2(a[2], a[3]);
    r.u[2] = pkbf2(b[0], b[1]); r.u[3] = pkbf2(b[2], b[3]);
    *(s16x8*)&lds[e ^ ((row & 7) << 3)] = r.v;
  }
  __syncthreads();

  // ---- sweep 1: Q^T, K^T = Wq/Wk @ X^T for head h ----
  f32x4 aq[2][4], ak[2][4];
#pragma unroll
  for (int t = 0; t < 2; ++t)
#pragma unroll
    for (int nj = 0; nj < 4; ++nj) {
      aq[t][nj] = f32x4{0.f, 0.f, 0.f, 0.f};
      ak[t][nj] = f32x4{0.f, 0.f, 0.f, 0.f};
    }
#pragma unroll
  for (int ks = 0; ks < 8; ++ks) {
    const int kof = ks * 32 + g * 8;
    s16x8 bx[4];
#pragma unroll
    for (int nj = 0; nj < 4; ++nj) {
      const int row = 16 * nj + c;
      bx[nj] = *(const s16x8*)&lds[(row * 256 + kof) ^ c7s];
    }
#pragma unroll
    for (int t = 0; t < 2; ++t) {
      s16x8 awq = *(const s16x8*)&wq_bf[(size_t)((2 * h + t) * 16 + c) * DM + kof];
      s16x8 awk = *(const s16x8*)&wq_bf[(size_t)((256 + 32 * h + 16 * t) + c) * DM + kof];
#pragma unroll
      for (int nj = 0; nj < 4; ++nj) {
        aq[t][nj] = __builtin_amdgcn_mfma_f32_16x16x32_bf16(awq, bx[nj], aq[t][nj], 0, 0, 0);
        ak[t][nj] = __builtin_amdgcn_mfma_f32_16x16x32_bf16(awk, bx[nj], ak[t][nj], 0, 0, 0);
      }
    }
  }
#pragma unroll
  for (int t = 0; t < 2; ++t) {
    f32x4 bq = *(const f32x4*)(bqkv + (2 * h + t) * 16 + 4 * g);
    f32x4 bk = *(const f32x4*)(bqkv + 256 + 32 * h + 16 * t + 4 * g);
#pragma unroll
    for (int nj = 0; nj < 4; ++nj) {
      aq[t][nj] += bq;
      ak[t][nj] += bk;
    }
  }

  // ---- Q,K fragments (in-register transpose) ----
  s16x8 qa[4], ka[4];
#pragma unroll
  for (int i = 0; i < 4; ++i) {
    qa[i] = xpose_frag(aq[0][i], aq[1][i], c, g);
    ka[i] = xpose_frag(ak[0][i], ak[1][i], c, g);
  }

  // ---- S^T = K @ Q^T ----
  f32x4 sa[4][4];  // (key = 16ki+4g+r, q = 16qi+c)
#pragma unroll
  for (int ki = 0; ki < 4; ++ki)
#pragma unroll
    for (int qi = 0; qi < 4; ++qi) {
      f32x4 z = f32x4{0.f, 0.f, 0.f, 0.f};
      sa[ki][qi] = __builtin_amdgcn_mfma_f32_16x16x32_bf16(ka[ki], qa[qi], z, 0, 0, 0);
    }

  // ---- softmax over keys ----
  const float sc = 0.17677669529663687f * 1.4426950408889634f;
  float inv[4];
#pragma unroll
  for (int qi = 0; qi < 4; ++qi) {
    float m = sa[0][qi][0];
#pragma unroll
    for (int ki = 0; ki < 4; ++ki)
#pragma unroll
      for (int r = 0; r < 4; ++r) m = fmaxf(m, sa[ki][qi][r]);
    m = fmaxf(m, __shfl_xor(m, 16));
    m = fmaxf(m, __shfl_xor(m, 32));
    float s = 0.0f;
#pragma unroll
    for (int ki = 0; ki < 4; ++ki)
#pragma unroll
      for (int r = 0; r < 4; ++r) {
        float pv = exp2f((sa[ki][qi][r] - m) * sc);
        sa[ki][qi][r] = pv;
        s += pv;
      }
    s += __shfl_xor(s, 16);
    s += __shfl_xor(s, 32);
    inv[qi] = 1.0f / s;
  }

  // ---- P fragments (normalized, in-register transpose) ----
  s16x8 pa[4][2];
#pragma unroll
  for (int mi = 0; mi < 4; ++mi) {
    const float iv = inv[mi];
#pragma unroll
    for (int ks2 = 0; ks2 < 2; ++ks2) {
      f32x4 v0 = sa[2 * ks2][mi] * iv;
      f32x4 v1 = sa[2 * ks2 + 1][mi] * iv;
      pa[mi][ks2] = xpose_frag(v0, v1, c, g);
    }
  }

  // ---- sweep 2: V = X @ Wv^T -> (seq = 16mt+4g+r, d = 16t+c) ----
  f32x4 av[4][2];
#pragma unroll
  for (int mt = 0; mt < 4; ++mt)
#pragma unroll
    for (int t = 0; t < 2; ++t) av[mt][t] = f32x4{0.f, 0.f, 0.f, 0.f};
#pragma unroll
  for (int ks = 0; ks < 8; ++ks) {
    const int kof = ks * 32 + g * 8;
    s16x8 bx[4];
#pragma unroll
    for (int mt = 0; mt < 4; ++mt) {
      const int row = 16 * mt + c;
      bx[mt] = *(const s16x8*)&lds[(row * 256 + kof) ^ c7s];
    }
#pragma unroll
    for (int t = 0; t < 2; ++t) {
      s16x8 wv = *(const s16x8*)&wq_bf[(size_t)(512 + 32 * h + 16 * t + c) * DM + kof];
#pragma unroll
      for (int mt = 0; mt < 4; ++mt)
        av[mt][t] = __builtin_amdgcn_mfma_f32_16x16x32_bf16(bx[mt], wv, av[mt][t], 0, 0, 0);
    }
  }
  // V bias (d-col = 16t + c)
  {
    const float bv0 = bqkv[512 + 32 * h + c];
    const float bv1 = bqkv[512 + 32 * h + 16 + c];
#pragma unroll
    for (int mt = 0; mt < 4; ++mt)
#pragma unroll
      for (int r = 0; r < 4; ++r) {
        av[mt][0][r] += bv0;
        av[mt][1][r] += bv1;
      }
  }

  // ---- V fragments (in-register transpose) ----
  s16x8 vb[2][2];  // [nd][ks2]
#pragma unroll
  for (int nd = 0; nd < 2; ++nd)
#pragma unroll
    for (int ks2 = 0; ks2 < 2; ++ks2)
      vb[nd][ks2] = xpose_frag(av[2 * ks2][nd], av[2 * ks2 + 1][nd], c, g);

  // ---- O = P @ V ----
  f32x4 oa[4][2];
#pragma unroll
  for (int mi = 0; mi < 4; ++mi)
#pragma unroll
    for (int nd = 0; nd < 2; ++nd) oa[mi][nd] = f32x4{0.f, 0.f, 0.f, 0.f};
#pragma unroll
  for (int ks2 = 0; ks2 < 2; ++ks2)
#pragma unroll
    for (int mi = 0; mi < 4; ++mi)
#pragma unroll
      for (int nd = 0; nd < 2; ++nd)
        oa[mi][nd] = __builtin_amdgcn_mfma_f32_16x16x32_bf16(pa[mi][ks2], vb[nd][ks2], oa[mi][nd], 0, 0, 0);

  unsigned obp[4][2][2];
#pragma unroll
  for (int mi = 0; mi < 4; ++mi)
#pragma unroll
    for (int nd = 0; nd < 2; ++nd) {
      obp[mi][nd][0] = pkbf2(oa[mi][nd][0], oa[mi][nd][1]);
      obp[mi][nd][1] = pkbf2(oa[mi][nd][2], oa[mi][nd][3]);
    }

  __syncthreads();  // all X reads done

  // scatter O into att[row][feat] over the X region
#pragma unroll
  for (int mi = 0; mi < 4; ++mi)
#pragma unroll
    for (int nd = 0; nd < 2; ++nd)
#pragma unroll
      for (int r = 0; r < 4; ++r) {
        const int q = 16 * mi + 4 * g + r;
        const int feat = h * 32 + 16 * nd + c;
        unsigned val = obp[mi][nd][r >> 1] >> (16 * (r & 1));
        lds[(q * 256 + feat) ^ ((q & 7) << 3)] = (unsigned short)val;
      }
  __syncthreads();

  // ---- Phase C: out^T = Wproj @ att^T (2 e-tiles per wave) ----
  f32x4 pacc[2][4];
#pragma unroll
  for (int ti = 0; ti < 2; ++ti)
#pragma unroll
    for (int nj = 0; nj < 4; ++nj) pacc[ti][nj] = f32x4{0.f, 0.f, 0.f, 0.f};

#pragma unroll
  for (int ks = 0; ks < 8; ++ks) {
    const int kof = ks * 32 + 8 * g;
    s16x8 bx[4];
#pragma unroll
    for (int nj = 0; nj < 4; ++nj) {
      const int row = 16 * nj + c;
      bx[nj] = *(const s16x8*)&lds[(row * 256 + kof) ^ c7s];
    }
#pragma unroll
    for (int ti = 0; ti < 2; ++ti) {
      const int e = (2 * w + ti) * 16 + c;
      s16x8 aw = *(const s16x8*)&wp_bf[(size_t)e * DM + kof];
#pragma unroll
      for (int nj = 0; nj < 4; ++nj)
        pacc[ti][nj] = __builtin_amdgcn_mfma_f32_16x16x32_bf16(aw, bx[nj], pacc[ti][nj], 0, 0, 0);
    }
  }

  __syncthreads();  // att reads done; reuse LDS as f32 half-tiles

  // ---- epilogue: two 32-row f32 halves, staged + coalesced stores ----
  float* ldsf = (float*)lds;
  float* __restrict__ ob = out + (size_t)bn * (S_LEN * DM);
#pragma unroll
  for (int H = 0; H < 2; ++H) {
#pragma unroll
    for (int ti = 0; ti < 2; ++ti) {
      const int e0 = (2 * w + ti) * 16 + 4 * g;
      f32x4 bp = *(const f32x4*)(bproj + e0);
#pragma unroll
      for (int nj = 2 * H; nj < 2 * H + 2; ++nj) {
        const int lr = 16 * (nj - 2 * H) + c;   // local row 0..31
        f32x4 v;
        v[0] = pacc[ti][nj][0] + bp[0];
        v[1] = pacc[ti][nj][1] + bp[1];
        v[2] = pacc[ti][nj][2] + bp[2];
        v[3] = pacc[ti][nj][3] + bp[3];
        *(f32x4*)&ldsf[(lr * 256 + e0) ^ ((lr & 7) << 2)] = v;
      }
    }
    __syncthreads();
#pragma unroll
    for (int it = 0; it < 4; ++it) {
      const int i = (it * 512 + tid) * 4;     // [0, 8192)
      const int lr = i >> 8;
      f32x4 v = *(const f32x4*)&ldsf[i ^ ((lr & 7) << 2)];
      *(f32x4*)(ob + H * 8192 + i) = v;
    }
    if (H == 0) __syncthreads();
  }
}

extern "C" void kernel_launch(void* const* d_in, const int* in_sizes, int n_in,
                              void* d_out, int out_size, void* d_ws, size_t ws_size,
                              hipStream_t stream) {
  (void)n_in; (void)ws_size; (void)out_size;
  const float* x     = (const float*)d_in[0];
  const float* wqkv  = (const float*)d_in[1];
  const float* bqkv  = (const float*)d_in[2];
  const float* wproj = (const float*)d_in[3];
  const float* bproj = (const float*)d_in[4];
  float* out = (float*)d_out;

  unsigned short* wsb = (unsigned short*)d_ws;
  const unsigned short* wq_bf = wsb;
  const unsigned short* wp_bf = wsb + NQKV;

  hipLaunchKernelGGL(ta_prep_weights, dim3(256), dim3(256), 0, stream, wqkv, wproj, wsb);

  const int bn_total = in_sizes[0] / (S_LEN * DM);  // 2600
  hipLaunchKernelGGL(ta_fused_kernel, dim3(bn_total), dim3(512), 0, stream,
                     x, wq_bf, bqkv, wp_bf, bproj, out);
}

// Round 6
// 311.483 us; speedup vs baseline: 1.8836x; 1.8836x over previous
//
#include <hip/hip_runtime.h>
#include <hip/hip_bf16.h>

// TemporalAttention fused kernel for MI355X (gfx950), round 6.
// Identical structure to round 5 (512 threads = 8 waves, ONE head per wave,
// single pass, all fragments via in-register transpose, LDS 32KB).
// ONLY change: __launch_bounds__(512,2) -> compiler VGPR cap 128 (empirical
// cap = 256/min_waves_per_EU). 128 VGPRs = no spills (proven round 2) and
// 4 waves/SIMD -> 2 blocks/CU -> 16 waves/CU (50% occupancy ceiling).

namespace {

constexpr int S_LEN = 64;
constexpr int DM    = 256;
constexpr int NQKV  = 3 * DM * DM;

typedef float f32x4 __attribute__((ext_vector_type(4)));
typedef short s16x8 __attribute__((ext_vector_type(8)));

union BF2 { __hip_bfloat162 h; unsigned u; };
__device__ __forceinline__ unsigned pkbf2(float a, float b) {
  float2 t; t.x = a; t.y = b;
  BF2 cv; cv.h = __float22bfloat162_rn(t);
  return cv.u;
}

// In-register fragment transpose (verified rounds 3/4/5). Source: two f32x4
// accumulators (idx = 4*gs + r along the transposed dim, same c). Target:
// s16x8 MFMA A/B-fragment for lane (g,c).
__device__ __forceinline__ s16x8 xpose_frag(f32x4 a0, f32x4 a1, int c, int g) {
  const int src0 = ((g & 1) << 5) + c;
  const int src1 = src0 + 16;
  unsigned p00 = pkbf2(a0[0], a0[1]);
  unsigned p01 = pkbf2(a0[2], a0[3]);
  unsigned p10 = pkbf2(a1[0], a1[1]);
  unsigned p11 = pkbf2(a1[2], a1[3]);
  const bool hi = (g & 2) != 0;
  unsigned w0a = (unsigned)__shfl((int)p00, src0);
  unsigned w0b = (unsigned)__shfl((int)p10, src0);
  unsigned w1a = (unsigned)__shfl((int)p01, src0);
  unsigned w1b = (unsigned)__shfl((int)p11, src0);
  unsigned w2a = (unsigned)__shfl((int)p00, src1);
  unsigned w2b = (unsigned)__shfl((int)p10, src1);
  unsigned w3a = (unsigned)__shfl((int)p01, src1);
  unsigned w3b = (unsigned)__shfl((int)p11, src1);
  union { s16x8 v; unsigned u[4]; } r;
  r.u[0] = hi ? w0b : w0a;
  r.u[1] = hi ? w1b : w1a;
  r.u[2] = hi ? w2b : w2a;
  r.u[3] = hi ? w3b : w3a;
  return r.v;
}

} // namespace

// ---- prep: f32 weights -> bf16 in workspace ----
__global__ void ta_prep_weights(const float* __restrict__ wqkv,
                                const float* __restrict__ wproj,
                                unsigned short* __restrict__ wsb) {
  const int i = (blockIdx.x * 256 + (int)threadIdx.x) * 4;
  f32x4 v = (i < NQKV) ? *(const f32x4*)(wqkv + i)
                       : *(const f32x4*)(wproj + (i - NQKV));
  unsigned u0 = pkbf2(v[0], v[1]);
  unsigned u1 = pkbf2(v[2], v[3]);
  *(uint2*)(wsb + i) = make_uint2(u0, u1);
}

__global__ void __launch_bounds__(512, 2)
ta_fused_kernel(const float* __restrict__ x,
                const unsigned short* __restrict__ wq_bf,   // [768][256] bf16
                const float* __restrict__ bqkv,
                const unsigned short* __restrict__ wp_bf,   // [256][256] bf16
                const float* __restrict__ bproj,
                float* __restrict__ out)
{
  // LDS 32KB: xls[64][256] bf16 (X, swizzled) -> att[64][256] -> f32 [32][256] halves.
  __shared__ __align__(16) unsigned short lds[16384];

  const int bn = blockIdx.x;
  const int tid = (int)threadIdx.x;
  const int w = tid >> 6;       // wave 0..7 = head
  const int l = tid & 63;
  const int g = l >> 4;
  const int c = l & 15;
  const int c7s = (c & 7) << 3;
  const int h = w;

  const float* __restrict__ xb = x + (size_t)bn * (S_LEN * DM);

  // ---- cooperative stage X -> LDS bf16 (swizzled) ----
#pragma unroll
  for (int it = 0; it < 4; ++it) {
    const int e = (it * 512 + tid) * 8;
    const int row = e >> 8;
    f32x4 a = *(const f32x4*)(xb + e);
    f32x4 b = *(const f32x4*)(xb + e + 4);
    union { s16x8 v; unsigned u[4]; } r;
    r.u[0] = pkbf2(a[0], a[1]); r.u[1] = pkbf2(a[2], a[3]);
    r.u[2] = pkbf2(b[0], b[1]); r.u[3] = pkbf2(b[2], b[3]);
    *(s16x8*)&lds[e ^ ((row & 7) << 3)] = r.v;
  }
  __syncthreads();

  // ---- sweep 1: Q^T, K^T = Wq/Wk @ X^T for head h ----
  f32x4 aq[2][4], ak[2][4];
#pragma unroll
  for (int t = 0; t < 2; ++t)
#pragma unroll
    for (int nj = 0; nj < 4; ++nj) {
      aq[t][nj] = f32x4{0.f, 0.f, 0.f, 0.f};
      ak[t][nj] = f32x4{0.f, 0.f, 0.f, 0.f};
    }
#pragma unroll
  for (int ks = 0; ks < 8; ++ks) {
    const int kof = ks * 32 + g * 8;
    s16x8 bx[4];
#pragma unroll
    for (int nj = 0; nj < 4; ++nj) {
      const int row = 16 * nj + c;
      bx[nj] = *(const s16x8*)&lds[(row * 256 + kof) ^ c7s];
    }
#pragma unroll
    for (int t = 0; t < 2; ++t) {
      s16x8 awq = *(const s16x8*)&wq_bf[(size_t)((2 * h + t) * 16 + c) * DM + kof];
      s16x8 awk = *(const s16x8*)&wq_bf[(size_t)((256 + 32 * h + 16 * t) + c) * DM + kof];
#pragma unroll
      for (int nj = 0; nj < 4; ++nj) {
        aq[t][nj] = __builtin_amdgcn_mfma_f32_16x16x32_bf16(awq, bx[nj], aq[t][nj], 0, 0, 0);
        ak[t][nj] = __builtin_amdgcn_mfma_f32_16x16x32_bf16(awk, bx[nj], ak[t][nj], 0, 0, 0);
      }
    }
  }
#pragma unroll
  for (int t = 0; t < 2; ++t) {
    f32x4 bq = *(const f32x4*)(bqkv + (2 * h + t) * 16 + 4 * g);
    f32x4 bk = *(const f32x4*)(bqkv + 256 + 32 * h + 16 * t + 4 * g);
#pragma unroll
    for (int nj = 0; nj < 4; ++nj) {
      aq[t][nj] += bq;
      ak[t][nj] += bk;
    }
  }

  // ---- Q,K fragments (in-register transpose) ----
  s16x8 qa[4], ka[4];
#pragma unroll
  for (int i = 0; i < 4; ++i) {
    qa[i] = xpose_frag(aq[0][i], aq[1][i], c, g);
    ka[i] = xpose_frag(ak[0][i], ak[1][i], c, g);
  }

  // ---- S^T = K @ Q^T ----
  f32x4 sa[4][4];  // (key = 16ki+4g+r, q = 16qi+c)
#pragma unroll
  for (int ki = 0; ki < 4; ++ki)
#pragma unroll
    for (int qi = 0; qi < 4; ++qi) {
      f32x4 z = f32x4{0.f, 0.f, 0.f, 0.f};
      sa[ki][qi] = __builtin_amdgcn_mfma_f32_16x16x32_bf16(ka[ki], qa[qi], z, 0, 0, 0);
    }

  // ---- softmax over keys ----
  const float sc = 0.17677669529663687f * 1.4426950408889634f;
  float inv[4];
#pragma unroll
  for (int qi = 0; qi < 4; ++qi) {
    float m = sa[0][qi][0];
#pragma unroll
    for (int ki = 0; ki < 4; ++ki)
#pragma unroll
      for (int r = 0; r < 4; ++r) m = fmaxf(m, sa[ki][qi][r]);
    m = fmaxf(m, __shfl_xor(m, 16));
    m = fmaxf(m, __shfl_xor(m, 32));
    float s = 0.0f;
#pragma unroll
    for (int ki = 0; ki < 4; ++ki)
#pragma unroll
      for (int r = 0; r < 4; ++r) {
        float pv = exp2f((sa[ki][qi][r] - m) * sc);
        sa[ki][qi][r] = pv;
        s += pv;
      }
    s += __shfl_xor(s, 16);
    s += __shfl_xor(s, 32);
    inv[qi] = 1.0f / s;
  }

  // ---- P fragments (normalized, in-register transpose) ----
  s16x8 pa[4][2];
#pragma unroll
  for (int mi = 0; mi < 4; ++mi) {
    const float iv = inv[mi];
#pragma unroll
    for (int ks2 = 0; ks2 < 2; ++ks2) {
      f32x4 v0 = sa[2 * ks2][mi] * iv;
      f32x4 v1 = sa[2 * ks2 + 1][mi] * iv;
      pa[mi][ks2] = xpose_frag(v0, v1, c, g);
    }
  }

  // ---- sweep 2: V = X @ Wv^T -> (seq = 16mt+4g+r, d = 16t+c) ----
  f32x4 av[4][2];
#pragma unroll
  for (int mt = 0; mt < 4; ++mt)
#pragma unroll
    for (int t = 0; t < 2; ++t) av[mt][t] = f32x4{0.f, 0.f, 0.f, 0.f};
#pragma unroll
  for (int ks = 0; ks < 8; ++ks) {
    const int kof = ks * 32 + g * 8;
    s16x8 bx[4];
#pragma unroll
    for (int mt = 0; mt < 4; ++mt) {
      const int row = 16 * mt + c;
      bx[mt] = *(const s16x8*)&lds[(row * 256 + kof) ^ c7s];
    }
#pragma unroll
    for (int t = 0; t < 2; ++t) {
      s16x8 wv = *(const s16x8*)&wq_bf[(size_t)(512 + 32 * h + 16 * t + c) * DM + kof];
#pragma unroll
      for (int mt = 0; mt < 4; ++mt)
        av[mt][t] = __builtin_amdgcn_mfma_f32_16x16x32_bf16(bx[mt], wv, av[mt][t], 0, 0, 0);
    }
  }
  // V bias (d-col = 16t + c)
  {
    const float bv0 = bqkv[512 + 32 * h + c];
    const float bv1 = bqkv[512 + 32 * h + 16 + c];
#pragma unroll
    for (int mt = 0; mt < 4; ++mt)
#pragma unroll
      for (int r = 0; r < 4; ++r) {
        av[mt][0][r] += bv0;
        av[mt][1][r] += bv1;
      }
  }

  // ---- V fragments (in-register transpose) ----
  s16x8 vb[2][2];  // [nd][ks2]
#pragma unroll
  for (int nd = 0; nd < 2; ++nd)
#pragma unroll
    for (int ks2 = 0; ks2 < 2; ++ks2)
      vb[nd][ks2] = xpose_frag(av[2 * ks2][nd], av[2 * ks2 + 1][nd], c, g);

  // ---- O = P @ V ----
  f32x4 oa[4][2];
#pragma unroll
  for (int mi = 0; mi < 4; ++mi)
#pragma unroll
    for (int nd = 0; nd < 2; ++nd) oa[mi][nd] = f32x4{0.f, 0.f, 0.f, 0.f};
#pragma unroll
  for (int ks2 = 0; ks2 < 2; ++ks2)
#pragma unroll
    for (int mi = 0; mi < 4; ++mi)
#pragma unroll
      for (int nd = 0; nd < 2; ++nd)
        oa[mi][nd] = __builtin_amdgcn_mfma_f32_16x16x32_bf16(pa[mi][ks2], vb[nd][ks2], oa[mi][nd], 0, 0, 0);

  unsigned obp[4][2][2];
#pragma unroll
  for (int mi = 0; mi < 4; ++mi)
#pragma unroll
    for (int nd = 0; nd < 2; ++nd) {
      obp[mi][nd][0] = pkbf2(oa[mi][nd][0], oa[mi][nd][1]);
      obp[mi][nd][1] = pkbf2(oa[mi][nd][2], oa[mi][nd][3]);
    }

  __syncthreads();  // all X reads done

  // scatter O into att[row][feat] over the X region
#pragma unroll
  for (int mi = 0; mi < 4; ++mi)
#pragma unroll
    for (int nd = 0; nd < 2; ++nd)
#pragma unroll
      for (int r = 0; r < 4; ++r) {
        const int q = 16 * mi + 4 * g + r;
        const int feat = h * 32 + 16 * nd + c;
        unsigned val = obp[mi][nd][r >> 1] >> (16 * (r & 1));
        lds[(q * 256 + feat) ^ ((q & 7) << 3)] = (unsigned short)val;
      }
  __syncthreads();

  // ---- Phase C: out^T = Wproj @ att^T (2 e-tiles per wave) ----
  f32x4 pacc[2][4];
#pragma unroll
  for (int ti = 0; ti < 2; ++ti)
#pragma unroll
    for (int nj = 0; nj < 4; ++nj) pacc[ti][nj] = f32x4{0.f, 0.f, 0.f, 0.f};

#pragma unroll
  for (int ks = 0; ks < 8; ++ks) {
    const int kof = ks * 32 + 8 * g;
    s16x8 bx[4];
#pragma unroll
    for (int nj = 0; nj < 4; ++nj) {
      const int row = 16 * nj + c;
      bx[nj] = *(const s16x8*)&lds[(row * 256 + kof) ^ c7s];
    }
#pragma unroll
    for (int ti = 0; ti < 2; ++ti) {
      const int e = (2 * w + ti) * 16 + c;
      s16x8 aw = *(const s16x8*)&wp_bf[(size_t)e * DM + kof];
#pragma unroll
      for (int nj = 0; nj < 4; ++nj)
        pacc[ti][nj] = __builtin_amdgcn_mfma_f32_16x16x32_bf16(aw, bx[nj], pacc[ti][nj], 0, 0, 0);
    }
  }

  __syncthreads();  // att reads done; reuse LDS as f32 half-tiles

  // ---- epilogue: two 32-row f32 halves, staged + coalesced stores ----
  float* ldsf = (float*)lds;
  float* __restrict__ ob = out + (size_t)bn * (S_LEN * DM);
#pragma unroll
  for (int H = 0; H < 2; ++H) {
#pragma unroll
    for (int ti = 0; ti < 2; ++ti) {
      const int e0 = (2 * w + ti) * 16 + 4 * g;
      f32x4 bp = *(const f32x4*)(bproj + e0);
#pragma unroll
      for (int nj = 2 * H; nj < 2 * H + 2; ++nj) {
        const int lr = 16 * (nj - 2 * H) + c;   // local row 0..31
        f32x4 v;
        v[0] = pacc[ti][nj][0] + bp[0];
        v[1] = pacc[ti][nj][1] + bp[1];
        v[2] = pacc[ti][nj][2] + bp[2];
        v[3] = pacc[ti][nj][3] + bp[3];
        *(f32x4*)&ldsf[(lr * 256 + e0) ^ ((lr & 7) << 2)] = v;
      }
    }
    __syncthreads();
#pragma unroll
    for (int it = 0; it < 4; ++it) {
      const int i = (it * 512 + tid) * 4;     // [0, 8192)
      const int lr = i >> 8;
      f32x4 v = *(const f32x4*)&ldsf[i ^ ((lr & 7) << 2)];
      *(f32x4*)(ob + H * 8192 + i) = v;
    }
    if (H == 0) __syncthreads();
  }
}

extern "C" void kernel_launch(void* const* d_in, const int* in_sizes, int n_in,
                              void* d_out, int out_size, void* d_ws, size_t ws_size,
                              hipStream_t stream) {
  (void)n_in; (void)ws_size; (void)out_size;
  const float* x     = (const float*)d_in[0];
  const float* wqkv  = (const float*)d_in[1];
  const float* bqkv  = (const float*)d_in[2];
  const float* wproj = (const float*)d_in[3];
  const float* bproj = (const float*)d_in[4];
  float* out = (float*)d_out;

  unsigned short* wsb = (unsigned short*)d_ws;
  const unsigned short* wq_bf = wsb;
  const unsigned short* wp_bf = wsb + NQKV;

  hipLaunchKernelGGL(ta_prep_weights, dim3(256), dim3(256), 0, stream, wqkv, wproj, wsb);

  const int bn_total = in_sizes[0] / (S_LEN * DM);  // 2600
  hipLaunchKernelGGL(ta_fused_kernel, dim3(bn_total), dim3(512), 0, stream,
                     x, wq_bf, bqkv, wp_bf, bproj, out);
}